// Round 5
// baseline (1411.772 us; speedup 1.0000x reference)
//
#include <hip/hip_runtime.h>

#define SE_C   256
#define SE_B   16
#define SE_HW  16384   // 128*128
#define NBLK   256     // one block per channel; handles that channel's plane for every batch
#define NTHR   512

typedef float fx4 __attribute__((ext_vector_type(4)));

// ---------------- Fused persistent SE kernel ----------------
// Block g owns channel g. For each batch b:
//   1. (pipelined) plane U[b,g] is loaded into registers one batch ahead
//   2. reduce -> z[b,g] (release-store), signal cnt[b]
//   3. block b (owner) spins until cnt[b]==256, computes fc -> s[b,:], sets done[b]
//   4. all blocks spin done[b], read s[b,g], scale FROM REGISTERS, nt-store out
// U is read from HBM exactly once; out written once. 256 blocks x 512 thr
// co-resident on 256 CUs (8 waves/CU) -> spin-waits are safe.
__global__ __launch_bounds__(NTHR, 2) void se_fused(const float* __restrict__ U,
                                                    const float* __restrict__ w_sq,  // [128,256]
                                                    const float* __restrict__ w_ex,  // [256,128]
                                                    float* __restrict__ out,
                                                    float* __restrict__ z,       // [B*C]
                                                    float* __restrict__ s,       // [B*C]
                                                    unsigned* __restrict__ cnt,  // [B]
                                                    unsigned* __restrict__ done) // [B]
{
    const int g = blockIdx.x;   // channel
    const int t = threadIdx.x;

    __shared__ float red[8];
    __shared__ float zb[SE_C];
    __shared__ float h[SE_C / 2];
    __shared__ float gbc;

    fx4 bufA[8], bufB[8];

    // prologue: load batch 0
    {
        const fx4* Up = (const fx4*)(U + (size_t)g * SE_HW);
        #pragma unroll
        for (int j = 0; j < 8; ++j) bufA[j] = Up[t + j * NTHR];
    }

    auto body = [&](int b, fx4 (&cur)[8], fx4 (&nxt)[8]) {
        // 1. issue next batch's loads (in flight during reduce/fc/scale)
        if (b + 1 < SE_B) {
            const fx4* Up = (const fx4*)(U + ((size_t)(b + 1) * SE_C + g) * SE_HW);
            #pragma unroll
            for (int j = 0; j < 8; ++j) nxt[j] = Up[t + j * NTHR];
        }

        // 2. reduce current plane (registers)
        float sum = 0.f;
        #pragma unroll
        for (int j = 0; j < 8; ++j) { fx4 v = cur[j]; sum += (v.x + v.y) + (v.z + v.w); }
        #pragma unroll
        for (int off = 32; off > 0; off >>= 1) sum += __shfl_down(sum, off, 64);
        const int lane = t & 63, wid = t >> 6;
        if (lane == 0) red[wid] = sum;
        __syncthreads();
        if (t == 0) {
            float tot = 0.f;
            #pragma unroll
            for (int w = 0; w < 8; ++w) tot += red[w];
            __hip_atomic_store(&z[b * SE_C + g], tot * (1.0f / SE_HW),
                               __ATOMIC_RELEASE, __HIP_MEMORY_SCOPE_AGENT);
            __hip_atomic_fetch_add(&cnt[b], 1u, __ATOMIC_ACQ_REL, __HIP_MEMORY_SCOPE_AGENT);
        }

        // 3. fc by owner block (g == b, blocks 0..15)
        if (g == b) {
            if (t == 0) {
                while (__hip_atomic_load(&cnt[b], __ATOMIC_ACQUIRE, __HIP_MEMORY_SCOPE_AGENT) < NBLK)
                    __builtin_amdgcn_s_sleep(1);
            }
            __syncthreads();
            if (t < SE_C)
                zb[t] = __hip_atomic_load(&z[b * SE_C + t], __ATOMIC_ACQUIRE, __HIP_MEMORY_SCOPE_AGENT);
            __syncthreads();
            if (t < SE_C / 2) {
                const float* wr = w_sq + t * SE_C;
                float acc = 0.f;
                #pragma unroll 8
                for (int k = 0; k < SE_C; ++k) acc = fmaf(wr[k], zb[k], acc);
                h[t] = fmaxf(acc, 0.f);
            }
            __syncthreads();
            if (t < SE_C) {
                const float* wr = w_ex + t * (SE_C / 2);
                float acc = 0.f;
                #pragma unroll 8
                for (int k = 0; k < SE_C / 2; ++k) acc = fmaf(wr[k], h[k], acc);
                float sg = 1.0f / (1.0f + expf(-acc));
                __hip_atomic_store(&s[b * SE_C + t], sg, __ATOMIC_RELEASE, __HIP_MEMORY_SCOPE_AGENT);
            }
            __syncthreads();   // drains the s-stores before flagging
            if (t == 0)
                __hip_atomic_store(&done[b], 1u, __ATOMIC_RELEASE, __HIP_MEMORY_SCOPE_AGENT);
        }

        // 4. wait for gate, scale from registers, stream out
        if (t == 0) {
            while (__hip_atomic_load(&done[b], __ATOMIC_ACQUIRE, __HIP_MEMORY_SCOPE_AGENT) == 0u)
                __builtin_amdgcn_s_sleep(1);
            gbc = __hip_atomic_load(&s[b * SE_C + g], __ATOMIC_ACQUIRE, __HIP_MEMORY_SCOPE_AGENT);
        }
        __syncthreads();
        const float gv = gbc;
        fx4* Op = (fx4*)(out + ((size_t)b * SE_C + g) * SE_HW);
        #pragma unroll
        for (int j = 0; j < 8; ++j) {
            fx4 v = cur[j] * gv;
            __builtin_nontemporal_store(v, Op + t + j * NTHR);
        }
        __syncthreads();   // gbc/red safe to overwrite next iteration
    };

    // alternate buffers with compile-time parity (rule #20: no runtime-indexed reg arrays)
    for (int b = 0; b < SE_B; b += 2) {
        body(b, bufA, bufB);
        body(b + 1, bufB, bufA);
    }
}

extern "C" void kernel_launch(void* const* d_in, const int* in_sizes, int n_in,
                              void* d_out, int out_size, void* d_ws, size_t ws_size,
                              hipStream_t stream) {
    const float* U    = (const float*)d_in[0];
    const float* w_sq = (const float*)d_in[1];
    const float* w_ex = (const float*)d_in[2];
    float* out = (float*)d_out;

    float*    z    = (float*)d_ws;                    // [4096]
    float*    s    = z + SE_B * SE_C;                 // [4096]
    unsigned* cnt  = (unsigned*)(s + SE_B * SE_C);    // [16]
    unsigned* done = cnt + SE_B;                      // [16]

    // zero the sync flags every launch (graph-safe, deterministic)
    hipMemsetAsync(cnt, 0, 2 * SE_B * sizeof(unsigned), stream);

    se_fused<<<NBLK, NTHR, 0, stream>>>(U, w_sq, w_ex, out, z, s, cnt, done);
}

// Round 6
// 418.059 us; speedup vs baseline: 3.3770x; 3.3770x over previous
//
#include <hip/hip_runtime.h>

#define SE_C    256
#define SE_B    16
#define SE_HW   16384          // 128*128
#define CHUNK_B 4              // batches per chunk (64 MiB of U -> fits L3 with headroom)
#define NCHUNK  (SE_B / CHUNK_B)

typedef float fx4 __attribute__((ext_vector_type(4)));

// ---------------- pool + inline fc (last finishing block per batch) ----------------
// grid = CHUNK_B*256 blocks, one per (b,c) plane of this chunk.
// Each block reduces its plane -> z[b,c]; the 256th finisher for batch b
// (atomicAdd ticket, NO spinning) computes the squeeze/excite for that batch.
__global__ __launch_bounds__(256) void se_pool_fc(const float* __restrict__ U,
                                                  const float* __restrict__ w_sq,  // [128,256]
                                                  const float* __restrict__ w_ex,  // [256,128]
                                                  float* __restrict__ z,
                                                  float* __restrict__ s,
                                                  unsigned* __restrict__ cnt,
                                                  int b0) {
    const int local = blockIdx.x;          // 0 .. CHUNK_B*256-1
    const int b = b0 + (local >> 8);
    const int c = local & 255;
    const int t = threadIdx.x;
    const size_t plane = (size_t)b * SE_C + c;

    const fx4* Up = (const fx4*)(U + plane * SE_HW);
    float sum = 0.f;
    #pragma unroll
    for (int k = 0; k < 16; ++k) {                      // 16*256*4 = 16384 floats
        fx4 v = Up[t + k * 256];
        sum += (v.x + v.y) + (v.z + v.w);
    }
    #pragma unroll
    for (int off = 32; off > 0; off >>= 1) sum += __shfl_down(sum, off, 64);

    __shared__ float wsum[4];
    __shared__ int isLast;
    const int lane = t & 63, wid = t >> 6;
    if (lane == 0) wsum[wid] = sum;
    __syncthreads();
    if (t == 0) {
        float tot = (wsum[0] + wsum[1]) + (wsum[2] + wsum[3]);
        __hip_atomic_store(&z[plane], tot * (1.0f / SE_HW),
                           __ATOMIC_RELEASE, __HIP_MEMORY_SCOPE_AGENT);
        unsigned prev = __hip_atomic_fetch_add(&cnt[b], 1u,
                           __ATOMIC_ACQ_REL, __HIP_MEMORY_SCOPE_AGENT);
        isLast = (prev == SE_C - 1);                    // ticket: no spin, no wait
    }
    __syncthreads();
    if (!isLast) return;

    // ---- this block saw all 256 z-values for batch b: do the fc once ----
    __shared__ float zb[SE_C];
    __shared__ float h[SE_C / 2];
    zb[t] = __hip_atomic_load(&z[(size_t)b * SE_C + t],
                              __ATOMIC_ACQUIRE, __HIP_MEMORY_SCOPE_AGENT);
    __syncthreads();
    if (t < SE_C / 2) {
        const float* wr = w_sq + t * SE_C;
        float acc = 0.f;
        #pragma unroll 8
        for (int k = 0; k < SE_C; ++k) acc = fmaf(wr[k], zb[k], acc);
        h[t] = fmaxf(acc, 0.f);
    }
    __syncthreads();
    {
        const float* wr = w_ex + t * (SE_C / 2);
        float acc = 0.f;
        #pragma unroll 8
        for (int k = 0; k < SE_C / 2; ++k) acc = fmaf(wr[k], h[k], acc);
        s[(size_t)b * SE_C + t] = 1.0f / (1.0f + expf(-acc));  // visible at kernel boundary
    }
}

// ---------------- scale: out = U * s[plane], re-read served by L3 ----------------
__global__ __launch_bounds__(256) void se_scale(const float* __restrict__ U,
                                                const float* __restrict__ s,
                                                float* __restrict__ out,
                                                int b0) {
    const size_t plane = (size_t)b0 * SE_C + blockIdx.x;
    const float g = s[plane];                            // uniform scalar per block
    const fx4* Up = (const fx4*)(U + plane * SE_HW);
    fx4* Op = (fx4*)(out + plane * SE_HW);
    const int t = threadIdx.x;

    #pragma unroll
    for (int k = 0; k < 16; ++k) {
        fx4 v = Up[t + k * 256] * g;
        __builtin_nontemporal_store(v, Op + t + k * 256);
    }
}

extern "C" void kernel_launch(void* const* d_in, const int* in_sizes, int n_in,
                              void* d_out, int out_size, void* d_ws, size_t ws_size,
                              hipStream_t stream) {
    const float* U    = (const float*)d_in[0];
    const float* w_sq = (const float*)d_in[1];
    const float* w_ex = (const float*)d_in[2];
    float* out = (float*)d_out;

    float*    z   = (float*)d_ws;                    // [4096]
    float*    s   = z + SE_B * SE_C;                 // [4096]
    unsigned* cnt = (unsigned*)(s + SE_B * SE_C);    // [16]

    hipMemsetAsync(cnt, 0, SE_B * sizeof(unsigned), stream);

    for (int c = 0; c < NCHUNK; ++c) {
        const int b0 = c * CHUNK_B;
        se_pool_fc<<<CHUNK_B * SE_C, 256, 0, stream>>>(U, w_sq, w_ex, z, s, cnt, b0);
        se_scale  <<<CHUNK_B * SE_C, 256, 0, stream>>>(U, s, out, b0);
    }
}

// Round 7
// 416.581 us; speedup vs baseline: 3.3890x; 1.0035x over previous
//
#include <hip/hip_runtime.h>

#define SE_C   256
#define SE_B   16
#define SE_HW  16384   // 128*128
#define NPLANE (SE_B * SE_C)

typedef float fx4 __attribute__((ext_vector_type(4)));

// ---------------- Kernel 1: pool + inline fc (ticket; no spinning) ----------------
// Full grid: 4096 blocks, one per (b,c) plane. Each block reduces its plane -> z.
// The 256th finisher per batch (atomicAdd ticket) computes squeeze/excite for
// that batch inline. Kernel boundary publishes s[] to the scale pass.
__global__ __launch_bounds__(256) void se_pool_fc(const float* __restrict__ U,
                                                  const float* __restrict__ w_sq,  // [128,256]
                                                  const float* __restrict__ w_ex,  // [256,128]
                                                  float* __restrict__ z,
                                                  float* __restrict__ s,
                                                  unsigned* __restrict__ cnt) {
    const int plane = blockIdx.x;
    const int b = plane >> 8;
    const int t = threadIdx.x;

    const fx4* Up = (const fx4*)(U + (size_t)plane * SE_HW);
    float sum = 0.f;
    #pragma unroll
    for (int k = 0; k < 16; ++k) {                      // 16*256*4 = 16384 floats
        fx4 v = Up[t + k * 256];
        sum += (v.x + v.y) + (v.z + v.w);
    }
    #pragma unroll
    for (int off = 32; off > 0; off >>= 1) sum += __shfl_down(sum, off, 64);

    __shared__ float wsum[4];
    __shared__ int isLast;
    const int lane = t & 63, wid = t >> 6;
    if (lane == 0) wsum[wid] = sum;
    __syncthreads();
    if (t == 0) {
        float tot = (wsum[0] + wsum[1]) + (wsum[2] + wsum[3]);
        __hip_atomic_store(&z[plane], tot * (1.0f / SE_HW),
                           __ATOMIC_RELEASE, __HIP_MEMORY_SCOPE_AGENT);
        unsigned prev = __hip_atomic_fetch_add(&cnt[b], 1u,
                           __ATOMIC_ACQ_REL, __HIP_MEMORY_SCOPE_AGENT);
        isLast = (prev == SE_C - 1);                    // ticket: last finisher, no wait
    }
    __syncthreads();
    if (!isLast) return;

    // ---- all 256 z-values of batch b are globally visible: fc once ----
    __shared__ float zb[SE_C];
    __shared__ float h[SE_C / 2];
    zb[t] = __hip_atomic_load(&z[(size_t)b * SE_C + t],
                              __ATOMIC_ACQUIRE, __HIP_MEMORY_SCOPE_AGENT);
    __syncthreads();
    if (t < SE_C / 2) {
        const float* wr = w_sq + t * SE_C;
        float acc = 0.f;
        #pragma unroll 8
        for (int k = 0; k < SE_C; ++k) acc = fmaf(wr[k], zb[k], acc);
        h[t] = fmaxf(acc, 0.f);
    }
    __syncthreads();
    {
        const float* wr = w_ex + t * (SE_C / 2);
        float acc = 0.f;
        #pragma unroll 8
        for (int k = 0; k < SE_C / 2; ++k) acc = fmaf(wr[k], h[k], acc);
        s[(size_t)b * SE_C + t] = 1.0f / (1.0f + expf(-acc));  // visible at kernel boundary
    }
}

// ---------------- Kernel 2: scale, REVERSE plane order ----------------
// Pool streamed planes 0->4095, so high planes are MRU in L3. Reading in
// reverse walks the LRU stack top-down -> maximal L3 hits on the re-read.
// nt-stores keep the output from evicting U.
__global__ __launch_bounds__(256) void se_scale(const float* __restrict__ U,
                                                const float* __restrict__ s,
                                                float* __restrict__ out) {
    const int plane = (NPLANE - 1) - blockIdx.x;         // reverse order
    const float g = s[plane];                            // uniform scalar per block
    const fx4* Up = (const fx4*)(U + (size_t)plane * SE_HW);
    fx4* Op = (fx4*)(out + (size_t)plane * SE_HW);
    const int t = threadIdx.x;

    #pragma unroll
    for (int k = 0; k < 16; ++k) {
        fx4 v = Up[t + k * 256] * g;
        __builtin_nontemporal_store(v, Op + t + k * 256);
    }
}

extern "C" void kernel_launch(void* const* d_in, const int* in_sizes, int n_in,
                              void* d_out, int out_size, void* d_ws, size_t ws_size,
                              hipStream_t stream) {
    const float* U    = (const float*)d_in[0];
    const float* w_sq = (const float*)d_in[1];
    const float* w_ex = (const float*)d_in[2];
    float* out = (float*)d_out;

    float*    z   = (float*)d_ws;                    // [4096]
    float*    s   = z + NPLANE;                      // [4096]
    unsigned* cnt = (unsigned*)(s + NPLANE);         // [16]

    hipMemsetAsync(cnt, 0, SE_B * sizeof(unsigned), stream);  // ticket reset (64 B)

    se_pool_fc<<<NPLANE, 256, 0, stream>>>(U, w_sq, w_ex, z, s, cnt);
    se_scale  <<<NPLANE, 256, 0, stream>>>(U, s, out);
}

// Round 8
// 135.453 us; speedup vs baseline: 10.4226x; 3.0755x over previous
//
#include <hip/hip_runtime.h>

#define SE_C   256
#define SE_B   16
#define SE_HW  16384   // 128*128
#define NPLANE (SE_B * SE_C)

typedef float fx4 __attribute__((ext_vector_type(4)));   // native vector for nt builtins

// ---------------- Kernel 1: global average pool per (b,c) plane ----------------
// No atomics anywhere (R7 lesson: agent-scope release/acquire per block = L2
// maintenance storm). Plain stores; kernel boundary publishes z.
__global__ __launch_bounds__(256) void se_pool(const float* __restrict__ U,
                                               float* __restrict__ z) {
    const int plane = blockIdx.x;                       // 0 .. B*C-1
    const fx4* Up = (const fx4*)(U + (size_t)plane * SE_HW);
    const int t = threadIdx.x;

    float sum = 0.f;
    #pragma unroll
    for (int k = 0; k < 16; ++k) {                      // 16 * 256 * 4 = 16384 floats
        fx4 v = Up[t + k * 256];
        sum += (v.x + v.y) + (v.z + v.w);
    }
    // wave (64-lane) shuffle reduce
    #pragma unroll
    for (int off = 32; off > 0; off >>= 1)
        sum += __shfl_down(sum, off, 64);

    __shared__ float wsum[4];
    const int lane = t & 63, wid = t >> 6;
    if (lane == 0) wsum[wid] = sum;
    __syncthreads();
    if (t == 0) {
        float tot = (wsum[0] + wsum[1]) + (wsum[2] + wsum[3]);
        z[plane] = tot * (1.0f / SE_HW);
    }
}

// ---------------- Kernel 2: squeeze (relu) -> excite (sigmoid) ----------------
// one block per batch element; 256 threads
__global__ __launch_bounds__(256) void se_fc(const float* __restrict__ z,
                                             const float* __restrict__ w_sq,  // [C/2, C]
                                             const float* __restrict__ w_ex,  // [C, C/2]
                                             float* __restrict__ s) {
    const int b = blockIdx.x;
    const int t = threadIdx.x;

    __shared__ float zb[SE_C];
    __shared__ float h[SE_C / 2];

    zb[t] = z[b * SE_C + t];
    __syncthreads();

    if (t < SE_C / 2) {
        const float* wr = w_sq + t * SE_C;
        float acc = 0.f;
        #pragma unroll 8
        for (int c = 0; c < SE_C; ++c) acc = fmaf(wr[c], zb[c], acc);
        h[t] = fmaxf(acc, 0.f);
    }
    __syncthreads();

    {
        const float* wr = w_ex + t * (SE_C / 2);
        float acc = 0.f;
        #pragma unroll 8
        for (int c = 0; c < SE_C / 2; ++c) acc = fmaf(wr[c], h[c], acc);
        s[b * SE_C + t] = 1.0f / (1.0f + expf(-acc));
    }
}

// ---------------- Kernel 3: out = U * s[plane], REVERSE plane order ----------------
// Pool streamed planes 0->4095; high planes are MRU in the 256 MiB L3. Reverse
// traversal walks the LRU stack top-down -> retained fraction becomes hits.
// nt-stores (non-allocating, verified R5) keep out from evicting U.
__global__ __launch_bounds__(256) void se_scale(const float* __restrict__ U,
                                                const float* __restrict__ s,
                                                float* __restrict__ out) {
    const int plane = (NPLANE - 1) - blockIdx.x;         // reverse order
    const float g = s[plane];                            // uniform scalar per block
    const fx4* Up = (const fx4*)(U + (size_t)plane * SE_HW);
    fx4* Op = (fx4*)(out + (size_t)plane * SE_HW);
    const int t = threadIdx.x;

    #pragma unroll
    for (int k = 0; k < 16; ++k) {
        fx4 v = Up[t + k * 256] * g;
        __builtin_nontemporal_store(v, Op + t + k * 256);
    }
}

extern "C" void kernel_launch(void* const* d_in, const int* in_sizes, int n_in,
                              void* d_out, int out_size, void* d_ws, size_t ws_size,
                              hipStream_t stream) {
    const float* U    = (const float*)d_in[0];
    const float* w_sq = (const float*)d_in[1];
    const float* w_ex = (const float*)d_in[2];
    float* out = (float*)d_out;

    float* z = (float*)d_ws;             // [4096]
    float* s = z + NPLANE;               // [4096]

    se_pool <<<NPLANE, 256, 0, stream>>>(U, z);
    se_fc   <<<SE_B,   256, 0, stream>>>(z, w_sq, w_ex, s);
    se_scale<<<NPLANE, 256, 0, stream>>>(U, s, out);
}